// Round 9
// baseline (1850.268 us; speedup 1.0000x reference)
//
#include <hip/hip_runtime.h>

#define Bn 32
#define Tn 512
#define Cn 8
#define Hn 256
#define Gn 1024            // 4*Hn
#define NTHR 256           // 4 waves; each wave is an independent actor (no loop barriers)
#define SLC  16            // slices per channel (WG owns 16 h; each wave 4 h x 4 gates)
#define NBLK (Cn*2*SLC)    // 256 workgroups -> 1 per CU
#define K2n  (Hn/2)        // 128 k-pairs
#define BUFS 4             // exchange buffers; coprime with tag period 3 -> exact freshness
#define EXU  (BUFS*Cn*K2n*Bn) // 8-byte units per layer exchange array
#define SLC4 (SLC*4)       // out-partial slots per (t,c): slice x wave

typedef __attribute__((ext_vector_type(8))) __bf16 bf16x8;
typedef __attribute__((ext_vector_type(8))) short  short8;
typedef __attribute__((ext_vector_type(4))) float  f32x4;
typedef __attribute__((ext_vector_type(4))) unsigned uintx4;
typedef unsigned long long u64;

__device__ __forceinline__ unsigned bfr(float f) {            // fp32 -> bf16 bits, RNE
    unsigned u = __float_as_uint(f);
    return (u + 0x7fffu + ((u >> 16) & 1u)) >> 16;
}
__device__ __forceinline__ float sigmf(float v)  { return 1.0f / (1.0f + __expf(-v)); }
__device__ __forceinline__ float tanh_f(float v) { return 1.0f - 2.0f / (__expf(2.0f * v) + 1.0f); }

__device__ __forceinline__ f32x4 mf(short8 a, short8 b, f32x4 c) {
    return __builtin_amdgcn_mfma_f32_16x16x32_bf16(
        __builtin_bit_cast(bf16x8, a), __builtin_bit_cast(bf16x8, b), c, 0, 0, 0);
}

// split 8 consecutive fp32 into bf16 hi + bf16 lo fragments
__device__ __forceinline__ void splitw(const float* __restrict__ p, short8& hi, short8& lo) {
    short8 h, l;
#pragma unroll
    for (int j = 0; j < 8; ++j) {
        const float v = p[j];
        const unsigned hb = bfr(v);
        h[j] = (short)hb;
        l[j] = (short)bfr(v - __uint_as_float(hb << 16));
    }
    hi = h; lo = l;
}

// agent-scope (Infinity-Cache) single-copy-atomic 8-byte ops.
// Tag and data travel in ONE atomic word -> no ordering/fence/scope assumptions.
__device__ __forceinline__ void ast64(u64* p, u64 v) {
    __hip_atomic_store(p, v, __ATOMIC_RELAXED, __HIP_MEMORY_SCOPE_AGENT);
}
__device__ __forceinline__ u64 ald64(const u64* p) {
    return __hip_atomic_load(p, __ATOMIC_RELAXED, __HIP_MEMORY_SCOPE_AGENT);
}

__global__ void __launch_bounds__(NTHR, 1)
lstm_mfma(const float* __restrict__ x,
          const float* __restrict__ Wih1, const float* __restrict__ Whh1,
          const float* __restrict__ bih1, const float* __restrict__ bhh1,
          const float* __restrict__ Wih2, const float* __restrict__ Whh2,
          const float* __restrict__ bih2, const float* __restrict__ bhh2,
          const float* __restrict__ Wlin, const float* __restrict__ blin,
          float* __restrict__ out, void* __restrict__ wsv, int use_part) {
    // Wih2 fragments in wave-private LDS (frees 64 VGPR; lane-linear 16B = conflict-free)
    __shared__ short8 w2lds[4][8][2][64];   // [wave][kk][hi/lo][lane] = 64 KiB
    __shared__ float  tb1[4][16][20];       // per-wave 16x16 gate transpose (pad 20)
    __shared__ float  tb2[4][16][20];

    // exchange arrays: [4 buf][C][K2=128][B=32] of (hi-pair dword, lo-pair dword)
    // lo-pair LSBs (u64 bits 32,48) carry tag (t mod 3)+1; 0 = unwritten. BUFS=4 with
    // tag period 3 (coprime): a tag match implies data from EXACTLY the expected step
    // (stale candidates are 12 steps old; per-actor validation bounds skew <= 2).
    u64* EX1 = (u64*)wsv;
    u64* EX2 = EX1 + EXU;
    float* part = (float*)(EX2 + EXU);      // [T][C][SLC4][B] out partials

    const int tid  = threadIdx.x;
    const int wg   = blockIdx.x;
    const int c    = wg & 7;               // channel
    const int s    = (wg >> 3) & 15;       // slice: h-indices s*16 .. s*16+15
    const int bh   = (wg >> 7) & 1;        // batch-half
    const int lane = tid & 63;
    const int w    = tid >> 6;             // wave = actor; owns h = s*16+w*4 .. +3
    const int n    = lane & 15;            // batch col (B-frag col) == cell batch
    const int q    = lane >> 4;            // quad
    const int bn   = bh * 16 + n;          // global batch

    // A-row packing (R6-verified): lane n holds gate-row (gate = n>>2, hoff = n&3);
    // global gate row g = gate*256 + s*16 + w*4 + hoff. Full K=256 per wave.
    const int grow = ((n >> 2) << 8) + s * 16 + w * 4 + (n & 3);
    const size_t wbase = (size_t)c * Gn * Hn + (size_t)grow * Hn + q * 8;

    short8 w1h[8], w1l[8], w3h[8], w3l[8];   // Whh1 + Whh2 in VGPRs (128)
#pragma unroll
    for (int kk = 0; kk < 8; ++kk) {
        splitw(Whh1 + wbase + kk * 32, w1h[kk], w1l[kk]);
        splitw(Whh2 + wbase + kk * 32, w3h[kk], w3l[kk]);
        short8 th, tl;                        // Wih2 -> LDS
        splitw(Wih2 + wbase + kk * 32, th, tl);
        w2lds[w][kk][0][lane] = th;
        w2lds[w][kk][1][lane] = tl;
    }

    // per-lane cell constants: this lane's cell is (h = s*16 + w*4 + q, b = bn)
    float wi1c[4], bs1c[4], bs2c[4];
#pragma unroll
    for (int tt = 0; tt < 4; ++tt) {
        const int g = tt * 256 + s * 16 + w * 4 + q;
        wi1c[tt] = Wih1[c * Gn + g];
        bs1c[tt] = bih1[c * Gn + g] + bhh1[c * Gn + g];
        bs2c[tt] = bih2[c * Gn + g] + bhh2[c * Gn + g];
    }
    const float wl = Wlin[c * Hn + s * 16 + w * 4 + q];
    const float bl = blin[c];

    __syncthreads();    // once, pre-loop (w2lds is wave-private; cheap insurance)

    float c1v = 0.0f, c2v = 0.0f;

    for (int t = 0; t <= Tn; ++t) {
        const bool doA = (t < Tn);      // layer-1 step t
        const bool doB = (t >= 1);      // layer-2 step t-1 (pipelined one behind)
        const int wb = t & 3, rb = (t + 3) & 3;
        const unsigned ctag = (unsigned)(t % 3) + 1u;
        const unsigned ptag = (unsigned)((t + 2) % 3) + 1u;
        const unsigned em = (ptag & 1u) | ((ptag & 2u) << 15);
        const unsigned cm = (ctag & 1u) | ((ctag & 2u) << 15);
        const bool chk1 = (t >= 1);     // t=0: memset zeros = h1[-1]=0
        const bool chk2 = (t >= 2);     // t<2: memset zeros = h2[-1]=0
        const float xv = doA ? x[((size_t)bn * Tn + t) * Cn + c] : 0.0f;

        const u64* E1 = EX1 + (size_t)(rb * Cn + c) * K2n * Bn;
        const u64* E2 = EX2 + (size_t)(rb * Cn + c) * K2n * Bn;

        // ---- phase A: poll E2 (h2[t-2]) full-K; phase B: Whh2 MFMAs; f2 dies ----
        f32x4 aa2 = {0,0,0,0}, ax2 = {0,0,0,0};
        {
            short8 f2h[8], f2l[8];
            for (;;) {
                unsigned bad = 0;
#pragma unroll
                for (int kk = 0; kk < 8; ++kk) {
                    uintx4 ah, al;
#pragma unroll
                    for (int j2 = 0; j2 < 4; ++j2) {
                        const int k2 = kk * 16 + q * 4 + j2;
                        const u64 v = ald64(E2 + (size_t)k2 * Bn + bn);
                        ah[j2] = (unsigned)v;
                        al[j2] = (unsigned)(v >> 32);
                        bad |= (al[j2] ^ em) & 0x00010001u;
                    }
                    f2h[kk] = __builtin_bit_cast(short8, ah);
                    f2l[kk] = __builtin_bit_cast(short8, al);
                }
                if (!chk2 || __all((int)(bad == 0))) break;
                __builtin_amdgcn_s_sleep(1);
            }
#pragma unroll
            for (int kk = 0; kk < 8; ++kk) {
                aa2 = mf(w3h[kk], f2h[kk], aa2);
                ax2 = mf(w3l[kk], f2h[kk], mf(w3h[kk], f2l[kk], ax2));
            }
        }

        // ---- phase C: poll E1 (h1[t-1]) full-K ----
        short8 f1h[8], f1l[8];
        for (;;) {
            unsigned bad = 0;
#pragma unroll
            for (int kk = 0; kk < 8; ++kk) {
                uintx4 ah, al;
#pragma unroll
                for (int j2 = 0; j2 < 4; ++j2) {
                    const int k2 = kk * 16 + q * 4 + j2;
                    const u64 v = ald64(E1 + (size_t)k2 * Bn + bn);
                    ah[j2] = (unsigned)v;
                    al[j2] = (unsigned)(v >> 32);
                    bad |= (al[j2] ^ em) & 0x00010001u;
                }
                f1h[kk] = __builtin_bit_cast(short8, ah);
                f1l[kk] = __builtin_bit_cast(short8, al);
            }
            if (!chk1 || __all((int)(bad == 0))) break;
            __builtin_amdgcn_s_sleep(1);
        }

        // ---- phase D: Wih2 (LDS weights) completes gates2; cell2; publish h2 EARLY ----
        if (doB) {
#pragma unroll
            for (int kk = 0; kk < 8; ++kk) {
                const short8 wh  = w2lds[w][kk][0][lane];
                const short8 wl8 = w2lds[w][kk][1][lane];
                aa2 = mf(wh, f1h[kk], aa2);
                ax2 = mf(wl8, f1h[kk], mf(wh, f1l[kk], ax2));
            }
            // in-wave 4x4 quad transpose (R6-verified), no barrier
            float* tb = &tb2[w][0][0];
#pragma unroll
            for (int r = 0; r < 4; ++r) tb[n * 20 + q * 4 + r] = aa2[r] + ax2[r];
            asm volatile("s_waitcnt lgkmcnt(0)" ::: "memory");
            float gv[4];
#pragma unroll
            for (int tt = 0; tt < 4; ++tt) gv[tt] = tb[n * 20 + tt * 4 + q];

            const float iv = sigmf (gv[0] + bs2c[0]);
            const float fv = sigmf (gv[1] + bs2c[1]);
            const float gg = tanh_f(gv[2] + bs2c[2]);
            const float ov = sigmf (gv[3] + bs2c[3]);
            c2v = fv * c2v + iv * gg;
            const float h2v = ov * tanh_f(c2v);

            const unsigned hb = bfr(h2v);
            const unsigned lb = bfr(h2v - __uint_as_float(hb << 16));
            const unsigned packed = (hb << 16) | lb;
            const unsigned nbp = (unsigned)__shfl_xor((int)packed, 16, 64);
            if (t < Tn && (q & 1) == 0) {        // final h2 has no reader
                const unsigned hip = (packed >> 16) | (nbp & 0xffff0000u);
                unsigned lop = (packed & 0xffffu) | (nbp << 16);
                lop = (lop & 0xFFFEFFFEu) | cm;  // steal lo LSBs for tag
                const int k2p = s * 8 + w * 2 + (q >> 1);
                ast64(EX2 + (size_t)(wb * Cn + c) * K2n * Bn + (size_t)k2p * Bn + bn,
                      (u64)hip | ((u64)lop << 32));
            }

            float pv = h2v * wl;                 // out partial over this wave's 4 h
            pv += __shfl_xor(pv, 16, 64);
            pv += __shfl_xor(pv, 32, 64);
            if (q == 0) {
                if (use_part) {
                    part[(((size_t)(t - 1) * Cn + c) * SLC4 + (s * 4 + w)) * Bn + bn] = pv;
                } else {
                    atomicAdd(&out[((size_t)bn * Tn + (t - 1)) * Cn + c],
                              pv + ((s == 0 && w == 0) ? bl : 0.0f));
                }
            }
        }

        // ---- phase E: Whh1 MFMAs; transpose; cell1; publish h1[t] ----
        if (doA) {
            f32x4 aa1 = {0,0,0,0}, ax1 = {0,0,0,0};
#pragma unroll
            for (int kk = 0; kk < 8; ++kk) {
                aa1 = mf(w1h[kk], f1h[kk], aa1);
                ax1 = mf(w1l[kk], f1h[kk], mf(w1h[kk], f1l[kk], ax1));
            }
            float* tb = &tb1[w][0][0];
#pragma unroll
            for (int r = 0; r < 4; ++r) tb[n * 20 + q * 4 + r] = aa1[r] + ax1[r];
            asm volatile("s_waitcnt lgkmcnt(0)" ::: "memory");
            float gv[4];
#pragma unroll
            for (int tt = 0; tt < 4; ++tt) gv[tt] = tb[n * 20 + tt * 4 + q];

            const float iv = sigmf (gv[0] + xv * wi1c[0] + bs1c[0]);
            const float fv = sigmf (gv[1] + xv * wi1c[1] + bs1c[1]);
            const float gg = tanh_f(gv[2] + xv * wi1c[2] + bs1c[2]);
            const float ov = sigmf (gv[3] + xv * wi1c[3] + bs1c[3]);
            c1v = fv * c1v + iv * gg;
            const float h1v = ov * tanh_f(c1v);

            const unsigned hb = bfr(h1v);
            const unsigned lb = bfr(h1v - __uint_as_float(hb << 16));
            const unsigned packed = (hb << 16) | lb;
            const unsigned nbp = (unsigned)__shfl_xor((int)packed, 16, 64);
            if ((q & 1) == 0) {
                const unsigned hip = (packed >> 16) | (nbp & 0xffff0000u);
                unsigned lop = (packed & 0xffffu) | (nbp << 16);
                lop = (lop & 0xFFFEFFFEu) | cm;
                const int k2p = s * 8 + w * 2 + (q >> 1);
                ast64(EX1 + (size_t)(wb * Cn + c) * K2n * Bn + (size_t)k2p * Bn + bn,
                      (u64)hip | ((u64)lop << 32));
            }
        }
    }
}

__global__ void reduce_out(const float* __restrict__ part, const float* __restrict__ blin,
                           float* __restrict__ out) {
    const int t = blockIdx.x;           // 512
    const int c = threadIdx.x >> 5;     // 8
    const int b = threadIdx.x & 31;     // 32
    float v = blin[c];
#pragma unroll
    for (int s4 = 0; s4 < SLC4; ++s4)
        v += part[(((size_t)t * Cn + c) * SLC4 + s4) * Bn + b];
    out[(b * Tn + t) * Cn + c] = v;
}

extern "C" void kernel_launch(void* const* d_in, const int* in_sizes, int n_in,
                              void* d_out, int out_size, void* d_ws, size_t ws_size,
                              hipStream_t stream) {
    const float* x    = (const float*)d_in[0];
    const float* Wih1 = (const float*)d_in[1];
    const float* Whh1 = (const float*)d_in[2];
    const float* bih1 = (const float*)d_in[3];
    const float* bhh1 = (const float*)d_in[4];
    const float* Wih2 = (const float*)d_in[5];
    const float* Whh2 = (const float*)d_in[6];
    const float* bih2 = (const float*)d_in[7];
    const float* bhh2 = (const float*)d_in[8];
    const float* Wlin = (const float*)d_in[9];
    const float* blin = (const float*)d_in[10];
    float* out = (float*)d_out;

    const size_t h_bytes    = (size_t)2 * EXU * sizeof(u64);                  // 2 MiB
    const size_t part_bytes = (size_t)Tn * Cn * SLC4 * Bn * sizeof(float);    // 32 MiB
    const int use_part = (ws_size >= h_bytes + part_bytes) ? 1 : 0;

    hipMemsetAsync(d_ws, 0, h_bytes, stream);   // zero h-exchange (tag 0 = unwritten)
    if (!use_part)
        hipMemsetAsync(d_out, 0, (size_t)out_size * sizeof(float), stream);

    lstm_mfma<<<NBLK, NTHR, 0, stream>>>(
        x, Wih1, Whh1, bih1, bhh1, Wih2, Whh2, bih2, bhh2, Wlin, blin, out, d_ws, use_part);

    if (use_part) {
        const float* part = (const float*)((const char*)d_ws + h_bytes);
        reduce_out<<<Tn, Cn * Bn, 0, stream>>>(part, blin, out);
    }
}